// Round 4
// baseline (289.394 us; speedup 1.0000x reference)
//
#include <hip/hip_runtime.h>
#include <math.h>

#define C_DIM 256
#define HWDIM 256
#define CH_STRIDE (HWDIM * HWDIM)      // 65536 floats between channels
#define R_DIM 32
#define PS_PITCH 257                   // 32 slots x 257 floats, conflict-free

// Block = 2 horizontally-adjacent 8x8 patches: region 8 rows x 16 cols x 256 ch.
// 512 threads = 8 waves. Lane: co = l>>5 (channel parity), rowpos = (l>>2)&7,
// f4c = l&3. Wave `wid` iter k handles channel c = wid*32 + 2k + co.
// Thread holds 16 float4 (64 VGPR); __launch_bounds__(512,4) -> 2 blocks/CU so
// one block's HBM phases overlap the other's compute phases.
__global__ __launch_bounds__(512, 4)
void lpa_fused_kernel(const float* __restrict__ x,
                      const float* __restrict__ gamma,
                      const float* __restrict__ beta,
                      const float* __restrict__ w1,
                      const float* __restrict__ w2,
                      float* __restrict__ out,
                      int nwg)
{
    __shared__ float sp[16 * 128];     // [chan-group][pixel] partial sums
    __shared__ float sq[16 * 128];     // [chan-group][pixel] partial sumsq
    __shared__ float ps[32 * PS_PITCH];// [slot][channel] pm partials (transposed)
    __shared__ float mu_s[128];
    __shared__ float rs_s[128];
    __shared__ float gs[C_DIM];
    __shared__ float bs[C_DIM];
    __shared__ float pm_s[2 * C_DIM];  // [patch][c]
    __shared__ float h_s[2 * R_DIM];   // [patch][r]
    __shared__ float2 AB_s[2 * C_DIM]; // [patch][c] = (gamma*gate, beta*gate)

    const int t    = threadIdx.x;
    const int wid  = t >> 6;
    const int lane = t & 63;
    const int co     = lane >> 5;        // channel parity
    const int rowpos = (lane >> 2) & 7;  // row in region
    const int f4c    = lane & 3;         // float4 column 0..3
    const int patch  = f4c >> 1;         // patch 0/1 within the pair
    const int p0     = rowpos * 16 + f4c * 4;   // first pixel (0..127)

    const int bid = blockIdx.x;
    // XCD-aware bijective swizzle (nwg % 8 == 0): spatially-adjacent groups on
    // one XCD so the two 64B-sharers of each 128B line merge in that L2.
    const int per_xcd = nwg >> 3;
    const int pid = (bid & 7) * per_xcd + (bid >> 3);

    const int b  = pid >> 9;             // 512 groups per image (32 gh x 16 gw)
    const int ij = pid & 511;
    const unsigned H0 = (unsigned)(ij >> 4) * 8u;
    const unsigned W0 = (unsigned)(ij & 15) * 16u;
    const unsigned baseb  = (unsigned)b * (C_DIM * CH_STRIDE);
    const unsigned rowoff = baseb + (H0 + rowpos) * HWDIM + W0 + (unsigned)f4c * 4u;
    const unsigned c0 = (unsigned)wid * 32u + (unsigned)co;  // + 2k per iter

    if (t < C_DIM) { gs[t] = gamma[t]; bs[t] = beta[t]; }

    const float* xb = x + rowoff + c0 * CH_STRIDE;

    // ---- Stage 1: load 16 float4 into regs + per-pixel partial stats ----
    float4 v[16];
    float s0 = 0.f, s1 = 0.f, s2 = 0.f, s3 = 0.f;
    float q0 = 0.f, q1 = 0.f, q2 = 0.f, q3 = 0.f;
#pragma unroll
    for (int k = 0; k < 16; ++k) {
        v[k] = *reinterpret_cast<const float4*>(xb + (unsigned)(2 * k) * CH_STRIDE);
        s0 += v[k].x; q0 += v[k].x * v[k].x;
        s1 += v[k].y; q1 += v[k].y * v[k].y;
        s2 += v[k].z; q2 += v[k].z * v[k].z;
        s3 += v[k].w; q3 += v[k].w * v[k].w;
    }
    const int grp = wid * 2 + co;        // 16 groups of 16 channels
    *reinterpret_cast<float4*>(&sp[grp * 128 + p0]) = make_float4(s0, s1, s2, s3);
    *reinterpret_cast<float4*>(&sq[grp * 128 + p0]) = make_float4(q0, q1, q2, q3);
    __syncthreads();

    // ---- Stage 2: finalize per-pixel LN stats (128 threads = 128 pixels) ----
    if (t < 128) {
        float s = 0.f, q = 0.f;
#pragma unroll
        for (int g = 0; g < 16; ++g) {
            s += sp[g * 128 + t];
            q += sq[g * 128 + t];
        }
        float mu  = s * (1.0f / 256.0f);
        float var = q * (1.0f / 256.0f) - mu * mu;
        mu_s[t] = mu;
        rs_s[t] = rsqrtf(var + 1e-5f);
    }
    __syncthreads();

    // ---- Stage 3a: per-channel weighted sums over this thread's 4 pixels ----
    const float4 mu4 = *reinterpret_cast<const float4*>(&mu_s[p0]);
    const float4 rs4 = *reinterpret_cast<const float4*>(&rs_s[p0]);
    const int slot = patch * 16 + (f4c & 1) + rowpos * 2;   // 0..31
#pragma unroll
    for (int k = 0; k < 16; ++k) {
        unsigned c = c0 + (unsigned)(2 * k);
        float wsum = rs4.x * (v[k].x - mu4.x) + rs4.y * (v[k].y - mu4.y)
                   + rs4.z * (v[k].z - mu4.z) + rs4.w * (v[k].w - mu4.w);
        ps[slot * PS_PITCH + c] = wsum;  // conflict-free: banks = (slot+c)%32
    }
    __syncthreads();

    // ---- Stage 3b: pm (512 threads = 2 patches x 256 channels) ----
    {
        const int pt = t >> 8;
        const int c  = t & 255;
        float s = 0.f;
#pragma unroll
        for (int sub = 0; sub < 16; ++sub) {
            s += ps[(pt * 16 + sub) * PS_PITCH + c];
        }
        pm_s[pt * C_DIM + c] = gs[c] * s * (1.0f / 64.0f) + bs[c];
    }
    __syncthreads();

    // ---- Stage 4a: h = silu(w1 @ pm) for 2 patches; w1 [32][256] row-major ----
    {
        const int pt = t >> 8;           // patch
        const int r  = (t >> 3) & 31;    // output row
        const int k8 = t & 7;            // 8-way dot split
        const float4* wrow = reinterpret_cast<const float4*>(w1 + r * C_DIM + k8 * 32);
        const float* pmk = &pm_s[pt * C_DIM + k8 * 32];
        float s = 0.f;
#pragma unroll
        for (int j = 0; j < 8; ++j) {
            float4 wv = wrow[j];
            float4 pv = *reinterpret_cast<const float4*>(pmk + j * 4);
            s += wv.x * pv.x + wv.y * pv.y + wv.z * pv.z + wv.w * pv.w;
        }
        s += __shfl_down(s, 4, 8);
        s += __shfl_down(s, 2, 8);
        s += __shfl_down(s, 1, 8);
        if (k8 == 0) {
            float sig = 1.0f / (1.0f + __expf(-s));
            h_s[pt * R_DIM + r] = s * sig;
        }
    }
    __syncthreads();

    // ---- Stage 4b: gate = sigmoid(w2 @ h); fold gamma/beta; w2 [256][32] ----
    {
        const int pt = t >> 8;
        const int c  = t & 255;
        const float4* wrow = reinterpret_cast<const float4*>(w2 + c * R_DIM);
        const float* hk = &h_s[pt * R_DIM];
        float s = 0.f;
#pragma unroll
        for (int j = 0; j < 8; ++j) {
            float4 wv = wrow[j];
            s += wv.x * hk[j * 4 + 0] + wv.y * hk[j * 4 + 1]
               + wv.z * hk[j * 4 + 2] + wv.w * hk[j * 4 + 3];
        }
        float gate = 1.0f / (1.0f + __expf(-s));
        AB_s[pt * C_DIM + c] = make_float2(gs[c] * gate, bs[c] * gate);
    }
    __syncthreads();

    // ---- Stage 5: out = (gamma*rstd*(x-mu) + beta) * gate, from registers ----
    float* ob = out + rowoff + c0 * CH_STRIDE;
#pragma unroll
    for (int k = 0; k < 16; ++k) {
        unsigned c = c0 + (unsigned)(2 * k);
        float2 ab = AB_s[patch * C_DIM + c];
        float4 o;
        o.x = ab.x * rs4.x * (v[k].x - mu4.x) + ab.y;
        o.y = ab.x * rs4.y * (v[k].y - mu4.y) + ab.y;
        o.z = ab.x * rs4.z * (v[k].z - mu4.z) + ab.y;
        o.w = ab.x * rs4.w * (v[k].w - mu4.w) + ab.y;
        *reinterpret_cast<float4*>(ob + (unsigned)(2 * k) * CH_STRIDE) = o;
    }
}

extern "C" void kernel_launch(void* const* d_in, const int* in_sizes, int n_in,
                              void* d_out, int out_size, void* d_ws, size_t ws_size,
                              hipStream_t stream) {
    const float* x     = (const float*)d_in[0];
    const float* gamma = (const float*)d_in[1];
    const float* beta  = (const float*)d_in[2];
    const float* w1    = (const float*)d_in[3];
    const float* w2    = (const float*)d_in[4];
    float* out = (float*)d_out;

    const int B = in_sizes[0] / (C_DIM * HWDIM * HWDIM);   // 8
    const int nwg = B * 512;                               // 4096 two-patch groups

    lpa_fused_kernel<<<nwg, 512, 0, stream>>>(x, gamma, beta, w1, w2, out, nwg);
}